// Round 16
// baseline (248.497 us; speedup 1.0000x reference)
//
#include <hip/hip_runtime.h>

// VectorQuantizer: X [16384][128] f32, E [128][8192] f32
// out (f32 flat): quantized [16384*128], encodings [16384*8192], indices [16384], loss [1]
// R16: single mega-kernel, block/wave role split.
//  - compute waves: NO stores, NO in-loop barriers (store backpressure can never
//    block them); direct-L2 B-frags; rolling-threshold gate; verify -> bestws.
//  - fill waves/blocks: pure contiguous NT-store streams (the proven-fast regime).
//  - 1.0-scatter + quantized + loss partials in finish_kernel (stream-ordered).
#define D 128
#define K 8192
#define N 16384
#define NCOMP 256
#define NPURE 256
#define ROWS 64              // rows per compute block
#define NCH 64               // 128-col chunks
#define THREADS 768          // 12 waves
#define CAND_CAP 2048
#define DELTA 0.5f
#define RMIN_INIT 0xFF800000u // fsort(+inf); NOT 0xFFFFFFFF (decodes to NaN)
#define UNITS_IB 20480       // f32x4 units per in-block fill agent (1024 agents)
#define UNITS_P  4096        // f32x4 units per pure-block fill agent (3072 agents)
// 1024*20480 + 3072*4096 = 33,554,432 = N*K/4 exactly

typedef __attribute__((ext_vector_type(4))) float f32x4;
typedef __attribute__((ext_vector_type(16))) float f32x16;
typedef __attribute__((ext_vector_type(8))) short short8;

__device__ __forceinline__ unsigned short f2bf(float f) {
    unsigned int b = __float_as_uint(f);
    return (unsigned short)((b + 0x7FFFu + ((b >> 16) & 1u)) >> 16);
}
__device__ __forceinline__ unsigned int fsort(float f) {
    unsigned int b = __float_as_uint(f);
    return b ^ ((unsigned int)((int)b >> 31) | 0x80000000u);
}
__device__ __forceinline__ float funsort(unsigned int u) {
    return __uint_as_float((u & 0x80000000u) ? (u ^ 0x80000000u) : ~u);
}

// ---- prep: E -> bf16 transposed e1t[k][d], f32 transposed e2t[k][d], enorm ----
__global__ __launch_bounds__(256) void prep_kernel(const float* __restrict__ E,
        unsigned short* __restrict__ e1t, float* __restrict__ e2t,
        float* __restrict__ enorm) {
    __shared__ float esum[8][32];
    const int t = threadIdx.x;
    const int kl = t & 31, dg = t >> 5;
    const int k = blockIdx.x * 32 + kl;
    float s = 0.f;
    __align__(16) unsigned short tmpb[16];
    __align__(16) float tmpf[16];
#pragma unroll
    for (int j = 0; j < 16; ++j) {
        float v = E[(size_t)(dg * 16 + j) * K + k];
        s += v * v;
        tmpb[j] = f2bf(v);
        tmpf[j] = v;
    }
    *(f32x4*)(e1t + (size_t)k * D + dg * 16) = *(const f32x4*)tmpb;
    *(f32x4*)(e1t + (size_t)k * D + dg * 16 + 8) = *(const f32x4*)(tmpb + 8);
    if (e2t) {
#pragma unroll
        for (int q = 0; q < 4; ++q)
            *(f32x4*)(e2t + (size_t)k * D + dg * 16 + 4 * q) = *(const f32x4*)(tmpf + 4 * q);
    }
    esum[dg][kl] = s;
    __syncthreads();
    if (t < 32) {
        float e = 0.f;
#pragma unroll
        for (int g = 0; g < 8; ++g) e += esum[g][t];
        enorm[blockIdx.x * 32 + t] = e;
    }
}

template<int E2T>
__global__ __launch_bounds__(THREADS) void mega_kernel(
        const float* __restrict__ X, const float* __restrict__ E,
        const unsigned short* __restrict__ e1t, const float* __restrict__ e2t,
        const float* __restrict__ enorm, float* __restrict__ enc,
        unsigned long long* __restrict__ bestws) {
    __shared__ unsigned long long cand[CAND_CAP];   // 16 KB
    __shared__ unsigned long long best[ROWS];
    __shared__ unsigned int rmin[ROWS];
    __shared__ int candn;

    const int t = threadIdx.x;
    const int wid = t >> 6, l = t & 63;
    const int l31 = l & 31, lh = l >> 5;
    const f32x4 z = {0.f, 0.f, 0.f, 0.f};
    f32x4* enc4 = (f32x4*)enc;

    if (blockIdx.x >= NCOMP) {
        // ---- pure fill block: 12 free-running store streams ----
        const int aid = (blockIdx.x - NCOMP) * 12 + wid;           // 0..3071
        f32x4* base = enc4 + (size_t)1024 * UNITS_IB + (size_t)aid * UNITS_P;
        for (int u = 0; u < UNITS_P / 64; ++u)                     // 64 iters
            __builtin_nontemporal_store(z, base + u * 64 + l);
        return;
    }

    const int rowbase = blockIdx.x * ROWS;
    if (t < ROWS) { rmin[t] = RMIN_INIT; best[t] = ~0ull; }
    if (t == 0) candn = 0;
    __syncthreads();   // B1

    if (wid < 8) {
        // ---- COMPUTE wave: rows rowbase+wr.., cols wc.. of each 128-chunk ----
        const int wr = (wid >> 2) * 32, wc = (wid & 3) * 32;
        short8 afr[8];
        {
            const int row = rowbase + wr + l31;
#pragma unroll
            for (int ks = 0; ks < 8; ++ks) {
                const float* xp = X + (size_t)row * D + ks * 16 + lh * 8;
                f32x4 v0 = *(const f32x4*)xp;
                f32x4 v1 = *(const f32x4*)(xp + 4);
                short8 a;
                a[0] = (short)f2bf(v0[0]); a[1] = (short)f2bf(v0[1]);
                a[2] = (short)f2bf(v0[2]); a[3] = (short)f2bf(v0[3]);
                a[4] = (short)f2bf(v1[0]); a[5] = (short)f2bf(v1[1]);
                a[6] = (short)f2bf(v1[2]); a[7] = (short)f2bf(v1[3]);
                afr[ks] = a;
            }
        }

        for (int ch = 0; ch < NCH; ++ch) {
            const int c = ch * 128 + wc + l31;
            short8 bf[8];
            const unsigned short* bp = e1t + (size_t)c * D + lh * 8;
#pragma unroll
            for (int ks = 0; ks < 8; ++ks)
                bf[ks] = *(const short8*)(bp + ks * 16);
            const float en = enorm[c];

            f32x16 acc;
#pragma unroll
            for (int r = 0; r < 16; ++r) acc[r] = 0.f;
#pragma unroll
            for (int ks = 0; ks < 8; ++ks)
                acc = __builtin_amdgcn_mfma_f32_32x32x16_bf16(afr[ks], bf[ks], acc, 0, 0, 0);
#pragma unroll
            for (int r = 0; r < 16; ++r)
                acc[r] = fmaf(-2.f, acc[r], en);   // d~ = en - 2*sim

            if (ch == 0) {
                float tmin[16];
#pragma unroll
                for (int r = 0; r < 16; ++r) tmin[r] = acc[r];
#pragma unroll
                for (int m = 1; m <= 16; m <<= 1)
#pragma unroll
                    for (int r = 0; r < 16; ++r)
                        tmin[r] = fminf(tmin[r], __shfl_xor(tmin[r], m, 64));
#pragma unroll
                for (int r = 0; r < 16; ++r) {
                    const int ro = wr + (r & 3) + 8 * (r >> 2) + 4 * lh;
                    if (acc[r] < tmin[r] + DELTA) {
                        int ci = atomicAdd(&candn, 1);
                        if (ci < CAND_CAP)
                            cand[ci] = ((unsigned long long)fsort(acc[r]) << 32) |
                                       ((unsigned long long)ro << 13) | (unsigned)c;
                    }
                    if (l31 == 0) atomicMin(&rmin[ro], fsort(tmin[r]));
                }
            } else {
                float thrv[16];
#pragma unroll
                for (int q = 0; q < 4; ++q) {
                    uint4 rv = *(const uint4*)&rmin[wr + 8 * q + 4 * lh];
                    thrv[4 * q + 0] = funsort(rv.x);
                    thrv[4 * q + 1] = funsort(rv.y);
                    thrv[4 * q + 2] = funsort(rv.z);
                    thrv[4 * q + 3] = funsort(rv.w);
                }
#pragma unroll
                for (int r = 0; r < 16; ++r) {
                    const int ro = wr + (r & 3) + 8 * (r >> 2) + 4 * lh;
                    if (acc[r] < thrv[r] + DELTA) {
                        int ci = atomicAdd(&candn, 1);
                        if (ci < CAND_CAP)
                            cand[ci] = ((unsigned long long)fsort(acc[r]) << 32) |
                                       ((unsigned long long)ro << 13) | (unsigned)c;
                        if (acc[r] < thrv[r])
                            atomicMin(&rmin[ro], fsort(acc[r]));
                    }
                }
            }
        }
    } else {
        // ---- in-block FILL agent: free-running contiguous NT stream ----
        const int aid = blockIdx.x * 4 + (wid - 8);                // 0..1023
        f32x4* base = enc4 + (size_t)aid * UNITS_IB;
        for (int u = 0; u < UNITS_IB / 64; ++u)                    // 320 iters
            __builtin_nontemporal_store(z, base + u * 64 + l);
    }

    __syncthreads();   // B2: cand/rmin final (fill waves' stores drain here too)

    // ---- exact f32 verification (all 12 waves) ----
    {
        int n = candn; if (n > CAND_CAP) n = CAND_CAP;
        for (int i = wid; i < n; i += 12) {
            const unsigned long long e = cand[i];
            const float dta = funsort((unsigned int)(e >> 32));
            const int ro = (int)((e >> 13) & 63u);
            const int col = (int)(e & 8191u);
            if (dta < funsort(rmin[ro]) + DELTA) {
                const int row = rowbase + ro;
                float x0 = X[(size_t)row * D + l];
                float x1 = X[(size_t)row * D + 64 + l];
                float e0, e1;
                if (E2T) {
                    e0 = e2t[(size_t)col * D + l];
                    e1 = e2t[(size_t)col * D + 64 + l];
                } else {
                    e0 = E[(size_t)l * K + col];
                    e1 = E[(size_t)(l + 64) * K + col];
                }
                float s = x0 * e0 + x1 * e1;
#pragma unroll
                for (int m = 1; m <= 32; m <<= 1) s += __shfl_xor(s, m, 64);
                if (l == 0) {
                    float dtx = enorm[col] - 2.f * s;
                    atomicMin(&best[ro],
                        ((unsigned long long)fsort(dtx) << 32) | (unsigned)col);
                }
            }
        }
    }
    __syncthreads();   // B3

    if (t < ROWS) bestws[rowbase + t] = best[t];
}

// ---- finish: indices, 1.0 scatter (after ALL zero-fill: stream order),
//      quantized, loss partials ----
template<int E2T>
__global__ __launch_bounds__(256) void finish_kernel(const float* __restrict__ X,
        const float* __restrict__ E, const float* __restrict__ e2t,
        const unsigned long long* __restrict__ bestws, float* __restrict__ out,
        float* __restrict__ partials) {
    const int t = threadIdx.x;
    const int rl = t >> 4, s = t & 15;
    const int row = blockIdx.x * 16 + rl;
    float* qout = out;
    float* enc = out + (size_t)N * D;
    float* idxout = enc + (size_t)N * K;
    const int k = (int)(bestws[row] & 8191ull);
    const float* xp = X + (size_t)row * D + s * 8;
    f32x4 xv0 = *(const f32x4*)xp;
    f32x4 xv1 = *(const f32x4*)(xp + 4);
    f32x4 q0, q1;
    float part = 0.f;
#pragma unroll
    for (int j = 0; j < 4; ++j) {
        float e0, e1;
        if (E2T) {
            e0 = e2t[(size_t)k * D + s * 8 + j];
            e1 = e2t[(size_t)k * D + s * 8 + 4 + j];
        } else {
            e0 = E[(size_t)(s * 8 + j) * K + k];
            e1 = E[(size_t)(s * 8 + 4 + j) * K + k];
        }
        float d0 = e0 - xv0[j];
        q0[j] = xv0[j] + d0; part += d0 * d0;
        float d1 = e1 - xv1[j];
        q1[j] = xv1[j] + d1; part += d1 * d1;
    }
    *(f32x4*)(qout + (size_t)row * D + s * 8) = q0;
    *(f32x4*)(qout + (size_t)row * D + s * 8 + 4) = q1;
#pragma unroll
    for (int m = 1; m <= 8; m <<= 1) part += __shfl_xor(part, m, 64);
    __shared__ float rr[16];
    if (s == 0) {
        idxout[row] = (float)k;
        enc[(size_t)row * K + k] = 1.0f;
        rr[rl] = part;
    }
    __syncthreads();
    if (t == 0) {
        float sum = 0.f;
#pragma unroll
        for (int i = 0; i < 16; ++i) sum += rr[i];
        partials[blockIdx.x] = sum;
    }
}

__global__ __launch_bounds__(256) void loss_kernel(const float* __restrict__ partials,
                                                   float* __restrict__ out) {
    __shared__ float red[256];
    const int t = threadIdx.x;
    red[t] = partials[t] + partials[t + 256] + partials[t + 512] + partials[t + 768];
    __syncthreads();
    for (int off = 128; off > 0; off >>= 1) {
        if (t < off) red[t] += red[t + off];
        __syncthreads();
    }
    if (t == 0) {
        float mean = red[0] / (float)((size_t)N * D);
        out[(size_t)N * D + (size_t)N * K + N] = mean + 0.25f * mean;
    }
}

extern "C" void kernel_launch(void* const* d_in, const int* in_sizes, int n_in,
                              void* d_out, int out_size, void* d_ws, size_t ws_size,
                              hipStream_t stream) {
    const float* X = (const float*)d_in[0];
    const float* E = (const float*)d_in[1];
    float* out = (float*)d_out;
    float* enc = out + (size_t)N * D;
    char* ws = (char*)d_ws;

    const size_t E1T_B = (size_t)K * D * 2;          // 2 MB
    const size_t E2T_B = (size_t)K * D * 4;          // 4 MB
    const bool use_e2t = ws_size >= E1T_B + E2T_B + 512 * 1024;

    unsigned short* e1t = (unsigned short*)ws;
    float* e2t; float* enorm;
    if (use_e2t) {
        e2t = (float*)(ws + E1T_B);
        enorm = (float*)(ws + E1T_B + E2T_B);
    } else {
        e2t = nullptr;
        enorm = (float*)(ws + E1T_B);
    }
    unsigned long long* bestws = (unsigned long long*)((char*)(enorm + K));  // 128 KB
    float* partials = (float*)(bestws + N);                                  // 4 KB

    hipLaunchKernelGGL(prep_kernel, dim3(K / 32), dim3(256), 0, stream,
                       E, e1t, e2t, enorm);
    if (use_e2t) {
        hipLaunchKernelGGL((mega_kernel<1>), dim3(NCOMP + NPURE), dim3(THREADS), 0, stream,
                           X, E, e1t, e2t, enorm, enc, bestws);
        hipLaunchKernelGGL((finish_kernel<1>), dim3(N / 16), dim3(256), 0, stream,
                           X, E, e2t, bestws, out, partials);
    } else {
        hipLaunchKernelGGL((mega_kernel<0>), dim3(NCOMP + NPURE), dim3(THREADS), 0, stream,
                           X, E, e1t, e2t, enorm, enc, bestws);
        hipLaunchKernelGGL((finish_kernel<0>), dim3(N / 16), dim3(256), 0, stream,
                           X, E, e2t, bestws, out, partials);
    }
    hipLaunchKernelGGL(loss_kernel, dim3(1), dim3(256), 0, stream, partials, out);
}